// Round 6
// baseline (268.435 us; speedup 1.0000x reference)
//
#include <hip/hip_runtime.h>

// Problem: img [B=256, C=3, H=224, W=224] f32; zero a 32x32 square per batch
// (all channels), copy the rest. ~308 MB traffic -> ~49 us floor @6.3 TB/s.
//
// Evidence so far:
//  - write-only fills: 6.6 TB/s at 9.6% occupancy (few persistent waves)
//  - EVERY one-shot-wave read+write kernel: 3.3-3.6 TB/s, independent of
//    occupancy (63%), HBM bytes (75 vs 154 MB), VALU (3%), forced MLP (r5)
//  - r5 proved per-wave burst-MLP + vmcnt(0) full drain doesn't help.
// Diagnosis: one-shot waves phase-serialize reads/writes and pay cold-start
// latency against tiny traffic. The untested structure is the AITER-style
// counted-vmcnt rolling pipeline: persistent waves, 4-deep load window,
// vmcnt NEVER drained to 0, stores ride along (3 allowed outstanding).
//
// Grid: 1792 blocks (7/CU) x 256 thr; each thread: 21 float4 across 3
// (plane,chunk) work units (uniform b,y0,x0 per unit). Exact coverage.
// Window math (issue order L0 L1 L2 L3 | W0 S0 L4 | W1 S1 L5 | ...):
//   at Wk, ops issued after Lk = min(3,20-k) loads + min(3,k) stores
//   -> s_waitcnt vmcnt(N), N in {3,4,5,6}; steady state vmcnt(6).
// All loads/waits volatile asm + memory clobber (store order pinned, no
// sink possible); sched_barrier(0) after each wait (rule #18).

#define SQ 32
#define B_ 256
#define C_ 3
#define H_ 224
#define W_ 224

#define W4 (W_ / 4)               // 56 float4 per row
#define PLANE4 (H_ * W4)          // 12544 float4 per (b,c) plane
#define SPLIT 7                   // chunks per plane
#define CHUNK4 (PLANE4 / SPLIT)   // 1792 float4 per chunk
#define TPB 256
// 768 planes * 7 chunks = 5376 units; 3 units/block -> 1792 blocks, 21 f4/thread

typedef float v4f __attribute__((ext_vector_type(4)));

template <int N>
__device__ __forceinline__ void vwait() {
    static_assert(N >= 3 && N <= 6, "window");
    if constexpr (N == 3) asm volatile("s_waitcnt vmcnt(3)" ::: "memory");
    else if constexpr (N == 4) asm volatile("s_waitcnt vmcnt(4)" ::: "memory");
    else if constexpr (N == 5) asm volatile("s_waitcnt vmcnt(5)" ::: "memory");
    else                       asm volatile("s_waitcnt vmcnt(6)" ::: "memory");
    __builtin_amdgcn_sched_barrier(0);   // keep consumers below the wait
}

__global__ __launch_bounds__(TPB) void rsd_kernel(const v4f* __restrict__ img,
                                                  const int* __restrict__ y_idx,
                                                  const int* __restrict__ x_idx,
                                                  v4f* __restrict__ out) {
    const int blk = (int)blockIdx.x;
    const int t   = (int)threadIdx.x;

    int base4[3], y0a[3], x0a[3], coff[3];
#pragma unroll
    for (int j = 0; j < 3; ++j) {
        const int u     = blk * 3 + j;          // work unit, uniform
        const int plane = u / SPLIT;            // uniform (b*C + c)
        const int chunk = u - plane * SPLIT;    // uniform
        const int b     = plane / C_;           // uniform
        y0a[j]   = y_idx[b];                    // uniform -> scalar
        x0a[j]   = x_idx[b];
        coff[j]  = chunk * CHUNK4;
        base4[j] = plane * PLANE4 + coff[j] + t;
    }

    v4f vb[4];   // 4-deep rolling window, constant indices only (rule #20)

#define ISSUE(K)                                                           \
    {                                                                      \
        constexpr int j_ = (K) / 7, it_ = (K) % 7;                         \
        asm volatile("global_load_dwordx4 %0, %1, off"                     \
                     : "=v"(vb[(K) & 3])                                   \
                     : "v"(img + base4[j_] + it_ * TPB)                    \
                     : "memory");                                          \
    }

#define CONSUME(K)                                                         \
    {                                                                      \
        constexpr int j_ = (K) / 7, it_ = (K) % 7;                         \
        vwait<((20 - (K)) < 3 ? (20 - (K)) : 3) + ((K) < 3 ? (K) : 3)>();  \
        v4f v = vb[(K) & 3];                                               \
        const int o4 = coff[j_] + it_ * TPB + t;                           \
        const int h  = o4 / W4;              /* magic-mul */               \
        const int w  = (o4 - h * W4) << 2;                                 \
        const int cx = w - x0a[j_];                                        \
        if ((unsigned)(h - y0a[j_]) < SQ) {                                \
            if ((unsigned)(cx + 0) < SQ) v.x = 0.0f;                       \
            if ((unsigned)(cx + 1) < SQ) v.y = 0.0f;                       \
            if ((unsigned)(cx + 2) < SQ) v.z = 0.0f;                       \
            if ((unsigned)(cx + 3) < SQ) v.w = 0.0f;                       \
        }                                                                  \
        out[base4[j_] + it_ * TPB] = v;                                    \
    }

    ISSUE(0) ISSUE(1) ISSUE(2) ISSUE(3)
    CONSUME(0)  ISSUE(4)
    CONSUME(1)  ISSUE(5)
    CONSUME(2)  ISSUE(6)
    CONSUME(3)  ISSUE(7)
    CONSUME(4)  ISSUE(8)
    CONSUME(5)  ISSUE(9)
    CONSUME(6)  ISSUE(10)
    CONSUME(7)  ISSUE(11)
    CONSUME(8)  ISSUE(12)
    CONSUME(9)  ISSUE(13)
    CONSUME(10) ISSUE(14)
    CONSUME(11) ISSUE(15)
    CONSUME(12) ISSUE(16)
    CONSUME(13) ISSUE(17)
    CONSUME(14) ISSUE(18)
    CONSUME(15) ISSUE(19)
    CONSUME(16) ISSUE(20)
    CONSUME(17)
    CONSUME(18)
    CONSUME(19)
    CONSUME(20)

#undef ISSUE
#undef CONSUME
}

extern "C" void kernel_launch(void* const* d_in, const int* in_sizes, int n_in,
                              void* d_out, int out_size, void* d_ws, size_t ws_size,
                              hipStream_t stream) {
    const v4f* img  = (const v4f*)d_in[0];
    const int* yidx = (const int*)d_in[1];
    const int* xidx = (const int*)d_in[2];
    v4f*       out  = (v4f*)d_out;

    // 1792 blocks x 256 threads x 21 float4 = 9,633,792 float4 = out_size/4.
    rsd_kernel<<<dim3(1792), TPB, 0, stream>>>(img, yidx, xidx, out);
}

// Round 7
// 250.874 us; speedup vs baseline: 1.0700x; 1.0700x over previous
//
#include <hip/hip_runtime.h>

// Problem: img [B=256, C=3, H=224, W=224] f32; zero a 32x32 square per batch
// (all channels), copy the rest. ~308 MB traffic.
//
// Rounds 0-6 elimination: one-shot (r0, ~86us kernel), compiler-batched
// (r1/r2, 92-93), SDMA (r4, ~97), asm burst MLP=7 (r5, ~88), counted-vmcnt
// rolling pipeline at 28 waves/CU = 112KB in flight/CU (r6, ~91) -- ALL land
// at 2.5-3.5 TB/s mixed R/W while write-only fills hit 6.6 TB/s. Wave-side
// parallelism, MLP, occupancy, HBM bytes, VALU all eliminated. Remaining
// suspect: L1/TCP allocate-on-miss path -- each wave64 dwordx4 load pins 16
// lines of MSHR state with ZERO reuse; ~64 line-MSHRs/CU caps in-flight
// loads at ~4KB/CU -> Little's law ~2.8 TB/s chip-wide, matching observed.
//
// This round: r0 EXACTLY (best total, 255.8) + ONE change: non-temporal
// loads (nt bit -> bypass L1 allocation; miss tracking moves to the deeper
// L2 path). Stores stay plain (fills prove plain stores hit 6.6 TB/s).

#define SQ 32
#define B_ 256
#define C_ 3
#define H_ 224
#define W_ 224

typedef float v4f __attribute__((ext_vector_type(4)));

__global__ __launch_bounds__(256) void rsd_kernel(const v4f* __restrict__ img,
                                                  const int* __restrict__ y_idx,
                                                  const int* __restrict__ x_idx,
                                                  v4f* __restrict__ out,
                                                  int total4) {
    int i4 = blockIdx.x * 256 + threadIdx.x;
    if (i4 >= total4) return;

    // Non-temporal: zero-reuse stream, skip L1 allocation (the suspected
    // MSHR bottleneck). Only change vs the round-0 baseline.
    v4f v = __builtin_nontemporal_load(&img[i4]);

    int i = i4 << 2;                 // flat element index of lane 0 of this float4
    int w = i % W_;                  // column of first element (W%4==0: same row)
    int t = i / W_;                  // row index within [B*C*H]
    int h = t % H_;
    int b = t / (C_ * H_);

    int y0 = y_idx[b];
    int x0 = x_idx[b];

    if ((unsigned)(h - y0) < SQ) {   // row inside square?
        int cx = w - x0;
        if ((unsigned)(cx + 0) < SQ) v.x = 0.0f;
        if ((unsigned)(cx + 1) < SQ) v.y = 0.0f;
        if ((unsigned)(cx + 2) < SQ) v.z = 0.0f;
        if ((unsigned)(cx + 3) < SQ) v.w = 0.0f;
    }

    out[i4] = v;                     // plain store
}

extern "C" void kernel_launch(void* const* d_in, const int* in_sizes, int n_in,
                              void* d_out, int out_size, void* d_ws, size_t ws_size,
                              hipStream_t stream) {
    const v4f* img  = (const v4f*)d_in[0];
    const int* yidx = (const int*)d_in[1];
    const int* xidx = (const int*)d_in[2];
    v4f*       out  = (v4f*)d_out;

    int total4 = out_size / 4;       // out_size is ELEMENT count; 9,633,792 float4
    int blocks = (total4 + 255) / 256;
    rsd_kernel<<<blocks, 256, 0, stream>>>(img, yidx, xidx, out, total4);
}